// Round 1
// baseline (369.771 us; speedup 1.0000x reference)
//
#include <hip/hip_runtime.h>
#include <math.h>

typedef unsigned short u16;
typedef __attribute__((ext_vector_type(8))) short bf16x8;
typedef __attribute__((ext_vector_type(4))) short s16x4;
typedef __attribute__((ext_vector_type(4))) float f32x4;

__device__ __forceinline__ u16 f2bf(float f) {
  union { float f; unsigned u; } v; v.f = f;
  unsigned r = v.u + 0x7FFFu + ((v.u >> 16) & 1u);   // RNE
  return (u16)(r >> 16);
}
__device__ __forceinline__ float bf2f(u16 h) {
  union { unsigned u; float f; } v; v.u = ((unsigned)h) << 16; return v.f;
}
__device__ __forceinline__ void gload_lds16(const void* g, void* l) {
  __builtin_amdgcn_global_load_lds((const __attribute__((address_space(1))) void*)g,
                                   (__attribute__((address_space(3))) void*)l, 16, 0, 0);
}

// ---------------- f32 -> bf16 weight cast ----------------
__global__ __launch_bounds__(256) void k_cvt(const float* __restrict__ s,
                                             u16* __restrict__ d, int n) {
  int i = (blockIdx.x * 256 + threadIdx.x) * 4;
  if (i >= n) return;
  float4 v = *(const float4*)(s + i);
  s16x4 o;
  o[0] = (short)f2bf(v.x); o[1] = (short)f2bf(v.y);
  o[2] = (short)f2bf(v.z); o[3] = (short)f2bf(v.w);
  *(s16x4*)(d + i) = o;
}

// ---------------- adaLN scale/shift: ss = tc @ w.T + b (one wave / output) ----------------
__global__ __launch_bounds__(256) void k_ss(const float* __restrict__ tc,
    const float* __restrict__ wa, const float* __restrict__ ba,
    const float* __restrict__ wb, const float* __restrict__ bb,
    float* __restrict__ ss1, float* __restrict__ ss2) {
  int wv = blockIdx.x * 4 + (threadIdx.x >> 6);   // 0..4095
  int l = threadIdx.x & 63;
  int which = wv >> 11;
  int rem = wv & 2047;
  int b = rem >> 10;
  int row = rem & 1023;
  const float* w = which ? wb : wa;
  const float4* t4 = (const float4*)(tc + b * 512);
  const float4* w4 = (const float4*)(w + (size_t)row * 512);
  float s = 0.f;
#pragma unroll
  for (int q = 0; q < 2; ++q) {
    float4 a = t4[l * 2 + q], c = w4[l * 2 + q];
    s += a.x * c.x + a.y * c.y + a.z * c.z + a.w * c.w;
  }
#pragma unroll
  for (int m = 32; m; m >>= 1) s += __shfl_xor(s, m);
  if (l == 0) {
    float bias = (which ? bb : ba)[row];
    (which ? ss2 : ss1)[b * 1024 + row] = s + bias;
  }
}

// ---------------- adaLN: out = (LN(x)*g+b)*(1+scale)+shift -> bf16 ----------------
__global__ __launch_bounds__(256) void k_adaln(const float* __restrict__ x,
    const float* __restrict__ g, const float* __restrict__ be,
    const float* __restrict__ ss, u16* __restrict__ out) {
  int r = blockIdx.x * 4 + (threadIdx.x >> 6);    // row 0..2047
  int l = threadIdx.x & 63;
  int b = r >> 10;
  const float4* x4 = (const float4*)(x + (size_t)r * 512);
  float4 v0 = x4[l * 2], v1 = x4[l * 2 + 1];
  float s = v0.x + v0.y + v0.z + v0.w + v1.x + v1.y + v1.z + v1.w;
  float s2 = v0.x*v0.x + v0.y*v0.y + v0.z*v0.z + v0.w*v0.w
           + v1.x*v1.x + v1.y*v1.y + v1.z*v1.z + v1.w*v1.w;
#pragma unroll
  for (int m = 32; m; m >>= 1) { s += __shfl_xor(s, m); s2 += __shfl_xor(s2, m); }
  float mu = s * (1.f / 512.f);
  float var = s2 * (1.f / 512.f) - mu * mu;
  float rstd = rsqrtf(var + 1e-5f);
  int c = l * 8;
  float4 g0 = *(const float4*)(g + c),  g1 = *(const float4*)(g + c + 4);
  float4 e0 = *(const float4*)(be + c), e1 = *(const float4*)(be + c + 4);
  const float* sb = ss + b * 1024;
  float4 sc0 = *(const float4*)(sb + c),       sc1 = *(const float4*)(sb + c + 4);
  float4 sh0 = *(const float4*)(sb + 512 + c), sh1 = *(const float4*)(sb + 512 + c + 4);
  float xe[8] = {v0.x,v0.y,v0.z,v0.w,v1.x,v1.y,v1.z,v1.w};
  float gg[8] = {g0.x,g0.y,g0.z,g0.w,g1.x,g1.y,g1.z,g1.w};
  float ee[8] = {e0.x,e0.y,e0.z,e0.w,e1.x,e1.y,e1.z,e1.w};
  float sc[8] = {sc0.x,sc0.y,sc0.z,sc0.w,sc1.x,sc1.y,sc1.z,sc1.w};
  float sh[8] = {sh0.x,sh0.y,sh0.z,sh0.w,sh1.x,sh1.y,sh1.z,sh1.w};
  bf16x8 o;
#pragma unroll
  for (int e = 0; e < 8; ++e) {
    float hv = (xe[e] - mu) * rstd * gg[e] + ee[e];
    float res = hv * (1.f + sc[e]) + sh[e];
    o[e] = (short)f2bf(res);
  }
  *(bf16x8*)(out + (size_t)r * 512 + c) = o;
}

// ---------------- bf16 MFMA GEMM: C[M,N] = A[M,K] @ Bw[N,K]^T, 128x128 tile ----------------
// MODE 0: bf16 out, scale cols<512 by qscale (fused QKV)
// MODE 1: f32 out = acc + cb[col] + add_[row,col]   (WO residual / FFN2 residual)
// MODE 2: bf16 out = gelu_exact(acc + cb[col])       (FFN1)
template<int MODE>
__global__ __launch_bounds__(256) void k_gemm(
    const u16* __restrict__ A, const u16* __restrict__ Bw,
    int M, int N, int K,
    u16* __restrict__ obf, float* __restrict__ of,
    const float* __restrict__ cb, const float* __restrict__ add_,
    float qscale) {
  __shared__ u16 la[128 * 64];
  __shared__ u16 lb[128 * 64];
  const int tid = threadIdx.x;
  const int l = tid & 63, w = tid >> 6;
  const int wr = w >> 1, wc = w & 1;
  const int m0 = blockIdx.y * 128, n0 = blockIdx.x * 128;
  f32x4 acc[4][4];
  const f32x4 fz = {0.f, 0.f, 0.f, 0.f};
#pragma unroll
  for (int m = 0; m < 4; ++m)
#pragma unroll
    for (int n = 0; n < 4; ++n) acc[m][n] = fz;
  const int nkt = K >> 6;
  for (int kt = 0; kt < nkt; ++kt) {
    const int k0 = kt * 64;
    __syncthreads();
#pragma unroll
    for (int r2 = 0; r2 < 4; ++r2) {
      unsigned e = r2 * 256 + tid;
      gload_lds16(A  + (size_t)(m0 + (e >> 3)) * K + k0 + (e & 7) * 8, la + (e & ~63u) * 8);
      gload_lds16(Bw + (size_t)(n0 + (e >> 3)) * K + k0 + (e & 7) * 8, lb + (e & ~63u) * 8);
    }
    __syncthreads();
#pragma unroll
    for (int kk = 0; kk < 2; ++kk) {
      bf16x8 af[4], bfr[4];
#pragma unroll
      for (int m = 0; m < 4; ++m)
        af[m] = *(const bf16x8*)(la + (wr * 64 + m * 16 + (l & 15)) * 64 + kk * 32 + (l >> 4) * 8);
#pragma unroll
      for (int n = 0; n < 4; ++n)
        bfr[n] = *(const bf16x8*)(lb + (wc * 64 + n * 16 + (l & 15)) * 64 + kk * 32 + (l >> 4) * 8);
#pragma unroll
      for (int m = 0; m < 4; ++m)
#pragma unroll
        for (int n = 0; n < 4; ++n)
          acc[m][n] = __builtin_amdgcn_mfma_f32_16x16x32_bf16(af[m], bfr[n], acc[m][n], 0, 0, 0);
    }
  }
  const int rb  = m0 + wr * 64 + ((l >> 4) * 4);
  const int cb0 = n0 + wc * 64 + (l & 15);
#pragma unroll
  for (int m = 0; m < 4; ++m)
#pragma unroll
    for (int n = 0; n < 4; ++n) {
      int gcol = cb0 + n * 16;
#pragma unroll
      for (int j = 0; j < 4; ++j) {
        int grow = rb + m * 16 + j;
        float v = acc[m][n][j];
        if (MODE == 0) {
          float scv = (gcol < 512) ? qscale : 1.f;
          obf[(size_t)grow * N + gcol] = f2bf(v * scv);
        } else if (MODE == 1) {
          of[(size_t)grow * N + gcol] = v + cb[gcol] + add_[(size_t)grow * N + gcol];
        } else {
          float t = v + cb[gcol];
          float ge = 0.5f * t * (1.f + erff(t * 0.70710678118654752f));
          obf[(size_t)grow * N + gcol] = f2bf(ge);
        }
      }
    }
}

// ---------------- pair bias: bias[b,h,i,j] = sum_c pair[b,i,j,c]*wp[h,c] -> bf16 ----------------
__global__ __launch_bounds__(256) void k_bias(const float* __restrict__ pair,
    const float* __restrict__ wp, u16* __restrict__ bias) {
  __shared__ float wl[1024];
  ((float4*)wl)[threadIdx.x] = ((const float4*)wp)[threadIdx.x];
  __syncthreads();
  size_t gid = (size_t)blockIdx.x * 256 + threadIdx.x;   // (b,i,j) flat, 2M total
  int j = (int)(gid & 1023);
  int i = (int)((gid >> 10) & 1023);
  int b = (int)(gid >> 20);
  const float4* p4 = (const float4*)(pair + (gid << 6));
  float acc[16];
#pragma unroll
  for (int h = 0; h < 16; ++h) acc[h] = 0.f;
#pragma unroll
  for (int c4 = 0; c4 < 16; ++c4) {
    float4 p = p4[c4];
#pragma unroll
    for (int h = 0; h < 16; ++h) {
      float4 wv = *(const float4*)(wl + h * 64 + c4 * 4);
      acc[h] = fmaf(p.x, wv.x, fmaf(p.y, wv.y, fmaf(p.z, wv.z, fmaf(p.w, wv.w, acc[h]))));
    }
  }
  size_t ob = (size_t)(b * 16) * 1048576 + (size_t)i * 1024 + (size_t)j;
#pragma unroll
  for (int h = 0; h < 16; ++h)
    bias[ob + (size_t)h * 1048576] = f2bf(acc[h]);
}

// ---------------- flash attention with additive bias; one block per (b,h,i-tile64) ----------------
__global__ __launch_bounds__(256) void k_attn(const u16* __restrict__ qkv,
    const u16* __restrict__ bias, u16* __restrict__ ob) {
  __shared__ u16 ql[64 * 32];
  __shared__ u16 kl[64 * 32];
  __shared__ u16 vt[32 * 64];     // V transposed [d][j]
  __shared__ u16 bl[64 * 64];     // bias tile [i][j]
  __shared__ u16 pl[4 * 16 * 64]; // per-wave P [16][64]
  const int tid = threadIdx.x, l = tid & 63, w = tid >> 6;
  const int i0 = blockIdx.x * 64;
  const int h  = blockIdx.y;
  const int b  = blockIdx.z;
  const u16* base = qkv + (size_t)b * 1024 * 1536 + h * 32;
  {
    int row = tid >> 2, d8 = (tid & 3) * 8;
    *(bf16x8*)(ql + row * 32 + d8) = *(const bf16x8*)(base + (size_t)(i0 + row) * 1536 + d8);
  }
  float mrun[4], lrun[4];
  f32x4 oa[2];
  const f32x4 fz = {0.f, 0.f, 0.f, 0.f};
#pragma unroll
  for (int r = 0; r < 4; ++r) { mrun[r] = -1e30f; lrun[r] = 0.f; }
  oa[0] = fz; oa[1] = fz;
  const size_t bbase = ((size_t)(b * 16 + h) * 1024 + (size_t)i0) * 1024;
  for (int jt = 0; jt < 16; ++jt) {
    const int j0 = jt * 64;
    __syncthreads();
    {
      int row = tid >> 2, d8 = (tid & 3) * 8;
      *(bf16x8*)(kl + row * 32 + d8) = *(const bf16x8*)(base + 512 + (size_t)(j0 + row) * 1536 + d8);
      bf16x8 vv = *(const bf16x8*)(base + 1024 + (size_t)(j0 + row) * 1536 + d8);
#pragma unroll
      for (int e = 0; e < 8; ++e) vt[(d8 + e) * 64 + row] = (u16)vv[e];
      int il = tid >> 2, jl = (tid & 3) * 16;
      const u16* bs = bias + bbase + (size_t)il * 1024 + j0 + jl;
      *(bf16x8*)(bl + il * 64 + jl)     = *(const bf16x8*)bs;
      *(bf16x8*)(bl + il * 64 + jl + 8) = *(const bf16x8*)(bs + 8);
    }
    __syncthreads();
    bf16x8 aq = *(const bf16x8*)(ql + (w * 16 + (l & 15)) * 32 + (l >> 4) * 8);
    f32x4 s[4];
#pragma unroll
    for (int n = 0; n < 4; ++n) {
      bf16x8 bk = *(const bf16x8*)(kl + (n * 16 + (l & 15)) * 32 + (l >> 4) * 8);
      s[n] = __builtin_amdgcn_mfma_f32_16x16x32_bf16(aq, bk, fz, 0, 0, 0);
    }
#pragma unroll
    for (int n = 0; n < 4; ++n)
#pragma unroll
      for (int r = 0; r < 4; ++r)
        s[n][r] += bf2f(bl[(w * 16 + (l >> 4) * 4 + r) * 64 + n * 16 + (l & 15)]);
    float p[4][4];
#pragma unroll
    for (int r = 0; r < 4; ++r) {
      float rm = fmaxf(fmaxf(s[0][r], s[1][r]), fmaxf(s[2][r], s[3][r]));
      rm = fmaxf(rm, __shfl_xor(rm, 1));
      rm = fmaxf(rm, __shfl_xor(rm, 2));
      rm = fmaxf(rm, __shfl_xor(rm, 4));
      rm = fmaxf(rm, __shfl_xor(rm, 8));
      float mn = fmaxf(mrun[r], rm);
      float corr = __expf(mrun[r] - mn);
      float rs = 0.f;
#pragma unroll
      for (int n = 0; n < 4; ++n) { p[n][r] = __expf(s[n][r] - mn); rs += p[n][r]; }
      rs += __shfl_xor(rs, 1); rs += __shfl_xor(rs, 2);
      rs += __shfl_xor(rs, 4); rs += __shfl_xor(rs, 8);
      lrun[r] = lrun[r] * corr + rs;
      mrun[r] = mn;
      oa[0][r] *= corr; oa[1][r] *= corr;
    }
#pragma unroll
    for (int n = 0; n < 4; ++n)
#pragma unroll
      for (int r = 0; r < 4; ++r)
        pl[w * 1024 + ((l >> 4) * 4 + r) * 64 + n * 16 + (l & 15)] = f2bf(p[n][r]);
    __syncthreads();
#pragma unroll
    for (int kk = 0; kk < 2; ++kk) {
      bf16x8 pa = *(const bf16x8*)(pl + w * 1024 + (l & 15) * 64 + kk * 32 + (l >> 4) * 8);
#pragma unroll
      for (int n = 0; n < 2; ++n) {
        bf16x8 vb = *(const bf16x8*)(vt + (n * 16 + (l & 15)) * 64 + kk * 32 + (l >> 4) * 8);
        oa[n] = __builtin_amdgcn_mfma_f32_16x16x32_bf16(pa, vb, oa[n], 0, 0, 0);
      }
    }
  }
#pragma unroll
  for (int n = 0; n < 2; ++n)
#pragma unroll
    for (int r = 0; r < 4; ++r) {
      float v = oa[n][r] / lrun[r];
      ob[(size_t)(b * 1024 + i0 + w * 16 + (l >> 4) * 4 + r) * 512 + h * 32 + n * 16 + (l & 15)] = f2bf(v);
    }
}

extern "C" void kernel_launch(void* const* d_in, const int* in_sizes, int n_in,
                              void* d_out, int out_size, void* d_ws, size_t ws_size,
                              hipStream_t stream) {
  const float* x    = (const float*)d_in[0];
  const float* pair = (const float*)d_in[1];
  const float* tc   = (const float*)d_in[2];
  const float* ln1g = (const float*)d_in[3];
  const float* ln1b = (const float*)d_in[4];
  const float* a1w  = (const float*)d_in[5];
  const float* a1b  = (const float*)d_in[6];
  const float* wq   = (const float*)d_in[7];
  const float* wk   = (const float*)d_in[8];
  const float* wv   = (const float*)d_in[9];
  const float* wp   = (const float*)d_in[10];
  const float* wo   = (const float*)d_in[11];
  const float* bo   = (const float*)d_in[12];
  const float* ln2g = (const float*)d_in[13];
  const float* ln2b = (const float*)d_in[14];
  const float* a2w  = (const float*)d_in[15];
  const float* a2b  = (const float*)d_in[16];
  const float* w1   = (const float*)d_in[17];
  const float* b1   = (const float*)d_in[18];
  const float* w2   = (const float*)d_in[19];
  const float* b2   = (const float*)d_in[20];
  float* out = (float*)d_out;

  char* ws = (char*)d_ws;
  size_t off = 0;
  auto alloc = [&](size_t bytes) {
    size_t cur = off;
    off += (bytes + 255) & ~(size_t)255;
    return (void*)(ws + cur);
  };
  float* ss1    = (float*)alloc(2 * 1024 * 4);
  float* ss2    = (float*)alloc(2 * 1024 * 4);
  u16*   qkvw   = (u16*)alloc((size_t)1536 * 512 * 2);
  u16*   wo_bf  = (u16*)alloc((size_t)512 * 512 * 2);
  u16*   w1_bf  = (u16*)alloc((size_t)2048 * 512 * 2);
  u16*   w2_bf  = (u16*)alloc((size_t)512 * 2048 * 2);
  u16*   h_bf   = (u16*)alloc((size_t)2048 * 512 * 2);
  u16*   qkv_bf = (u16*)alloc((size_t)2048 * 1536 * 2);
  u16*   o_bf   = (u16*)alloc((size_t)2048 * 512 * 2);
  u16*   h2_bf  = (u16*)alloc((size_t)2048 * 512 * 2);
  float* xmid   = (float*)alloc((size_t)2048 * 512 * 4);
  u16*   mid_bf = (u16*)alloc((size_t)2048 * 2048 * 2);
  u16*   bias_bf= (u16*)alloc((size_t)2 * 16 * 1024 * 1024 * 2);
  (void)ws_size; (void)in_sizes; (void)n_in; (void)out_size;

  // weights -> bf16 (qkv concatenated [1536,512])
  k_cvt<<<256, 256, 0, stream>>>(wq, qkvw, 262144);
  k_cvt<<<256, 256, 0, stream>>>(wk, qkvw + 262144, 262144);
  k_cvt<<<256, 256, 0, stream>>>(wv, qkvw + 524288, 262144);
  k_cvt<<<256, 256, 0, stream>>>(wo, wo_bf, 262144);
  k_cvt<<<1024, 256, 0, stream>>>(w1, w1_bf, 1048576);
  k_cvt<<<1024, 256, 0, stream>>>(w2, w2_bf, 1048576);

  // adaLN scale/shift for both blocks
  k_ss<<<1024, 256, 0, stream>>>(tc, a1w, a1b, a2w, a2b, ss1, ss2);

  // adaLN1 -> h (bf16)
  k_adaln<<<512, 256, 0, stream>>>(x, ln1g, ln1b, ss1, h_bf);

  // fused QKV GEMM: [2048,512]x[1536,512]^T -> qkv (q pre-scaled by 1/sqrt(32))
  k_gemm<0><<<dim3(12, 16), 256, 0, stream>>>(h_bf, qkvw, 2048, 1536, 512,
      qkv_bf, nullptr, nullptr, nullptr, 0.17677669529663687f);

  // pair bias -> bf16 [B,H,L,L]
  k_bias<<<8192, 256, 0, stream>>>(pair, wp, bias_bf);

  // flash attention
  k_attn<<<dim3(16, 16, 2), 256, 0, stream>>>(qkv_bf, bias_bf, o_bf);

  // out proj + residual: xmid = x + O@wo^T + bo (f32)
  k_gemm<1><<<dim3(4, 16), 256, 0, stream>>>(o_bf, wo_bf, 2048, 512, 512,
      nullptr, xmid, bo, x, 1.f);

  // adaLN2 -> h2 (bf16)
  k_adaln<<<512, 256, 0, stream>>>(xmid, ln2g, ln2b, ss2, h2_bf);

  // FFN1 + exact GELU -> mid (bf16)
  k_gemm<2><<<dim3(16, 16), 256, 0, stream>>>(h2_bf, w1_bf, 2048, 2048, 512,
      mid_bf, nullptr, b1, nullptr, 1.f);

  // FFN2 + residual -> out (f32)
  k_gemm<1><<<dim3(4, 16), 256, 0, stream>>>(mid_bf, w2_bf, 2048, 512, 2048,
      nullptr, out, b2, xmid, 1.f);
}

// Round 2
// 279.770 us; speedup vs baseline: 1.3217x; 1.3217x over previous
//
#include <hip/hip_runtime.h>
#include <math.h>

typedef unsigned short u16;
typedef __attribute__((ext_vector_type(8))) short bf16x8;
typedef __attribute__((ext_vector_type(4))) short s16x4;
typedef __attribute__((ext_vector_type(4))) float f32x4;

__device__ __forceinline__ u16 f2bf(float f) {
  union { float f; unsigned u; } v; v.f = f;
  unsigned r = v.u + 0x7FFFu + ((v.u >> 16) & 1u);   // RNE
  return (u16)(r >> 16);
}
__device__ __forceinline__ float bf2f(u16 h) {
  union { unsigned u; float f; } v; v.u = ((unsigned)h) << 16; return v.f;
}
__device__ __forceinline__ void gload_lds16(const void* g, void* l) {
  __builtin_amdgcn_global_load_lds((const __attribute__((address_space(1))) void*)g,
                                   (__attribute__((address_space(3))) void*)l, 16, 0, 0);
}

// ---------------- merged f32 -> bf16 weight cast (one launch) ----------------
__global__ __launch_bounds__(256) void k_cvt_all(
    const float* __restrict__ wq, const float* __restrict__ wk,
    const float* __restrict__ wv, const float* __restrict__ wo,
    const float* __restrict__ w1, const float* __restrict__ w2,
    u16* __restrict__ qkvw, u16* __restrict__ wo_bf,
    u16* __restrict__ w1_bf, u16* __restrict__ w2_bf) {
  int i = (blockIdx.x * 256 + threadIdx.x) * 4;   // element index, total 3145728
  const float* s; u16* d;
  if (i < 786432) {
    d = qkvw + i;
    if (i < 262144) s = wq + i;
    else if (i < 524288) s = wk + (i - 262144);
    else s = wv + (i - 524288);
  } else if (i < 1048576) { s = wo + (i - 786432); d = wo_bf + (i - 786432); }
  else if (i < 2097152)   { s = w1 + (i - 1048576); d = w1_bf + (i - 1048576); }
  else                    { s = w2 + (i - 2097152); d = w2_bf + (i - 2097152); }
  float4 v = *(const float4*)s;
  s16x4 o;
  o[0] = (short)f2bf(v.x); o[1] = (short)f2bf(v.y);
  o[2] = (short)f2bf(v.z); o[3] = (short)f2bf(v.w);
  *(s16x4*)d = o;
}

// ---------------- adaLN scale/shift: ss = tc @ w.T + b (one wave / output) ----------------
__global__ __launch_bounds__(256) void k_ss(const float* __restrict__ tc,
    const float* __restrict__ wa, const float* __restrict__ ba,
    const float* __restrict__ wb, const float* __restrict__ bb,
    float* __restrict__ ss1, float* __restrict__ ss2) {
  int wv = blockIdx.x * 4 + (threadIdx.x >> 6);   // 0..4095
  int l = threadIdx.x & 63;
  int which = wv >> 11;
  int rem = wv & 2047;
  int b = rem >> 10;
  int row = rem & 1023;
  const float* w = which ? wb : wa;
  const float4* t4 = (const float4*)(tc + b * 512);
  const float4* w4 = (const float4*)(w + (size_t)row * 512);
  float s = 0.f;
#pragma unroll
  for (int q = 0; q < 2; ++q) {
    float4 a = t4[l * 2 + q], c = w4[l * 2 + q];
    s += a.x * c.x + a.y * c.y + a.z * c.z + a.w * c.w;
  }
#pragma unroll
  for (int m = 32; m; m >>= 1) s += __shfl_xor(s, m);
  if (l == 0) {
    float bias = (which ? bb : ba)[row];
    (which ? ss2 : ss1)[b * 1024 + row] = s + bias;
  }
}

// ---------------- adaLN: out = (LN(x)*g+b)*(1+scale)+shift -> bf16 ----------------
__global__ __launch_bounds__(256) void k_adaln(const float* __restrict__ x,
    const float* __restrict__ g, const float* __restrict__ be,
    const float* __restrict__ ss, u16* __restrict__ out) {
  int r = blockIdx.x * 4 + (threadIdx.x >> 6);    // row 0..2047
  int l = threadIdx.x & 63;
  int b = r >> 10;
  const float4* x4 = (const float4*)(x + (size_t)r * 512);
  float4 v0 = x4[l * 2], v1 = x4[l * 2 + 1];
  float s = v0.x + v0.y + v0.z + v0.w + v1.x + v1.y + v1.z + v1.w;
  float s2 = v0.x*v0.x + v0.y*v0.y + v0.z*v0.z + v0.w*v0.w
           + v1.x*v1.x + v1.y*v1.y + v1.z*v1.z + v1.w*v1.w;
#pragma unroll
  for (int m = 32; m; m >>= 1) { s += __shfl_xor(s, m); s2 += __shfl_xor(s2, m); }
  float mu = s * (1.f / 512.f);
  float var = s2 * (1.f / 512.f) - mu * mu;
  float rstd = rsqrtf(var + 1e-5f);
  int c = l * 8;
  float4 g0 = *(const float4*)(g + c),  g1 = *(const float4*)(g + c + 4);
  float4 e0 = *(const float4*)(be + c), e1 = *(const float4*)(be + c + 4);
  const float* sb = ss + b * 1024;
  float4 sc0 = *(const float4*)(sb + c),       sc1 = *(const float4*)(sb + c + 4);
  float4 sh0 = *(const float4*)(sb + 512 + c), sh1 = *(const float4*)(sb + 512 + c + 4);
  float xe[8] = {v0.x,v0.y,v0.z,v0.w,v1.x,v1.y,v1.z,v1.w};
  float gg[8] = {g0.x,g0.y,g0.z,g0.w,g1.x,g1.y,g1.z,g1.w};
  float ee[8] = {e0.x,e0.y,e0.z,e0.w,e1.x,e1.y,e1.z,e1.w};
  float sc[8] = {sc0.x,sc0.y,sc0.z,sc0.w,sc1.x,sc1.y,sc1.z,sc1.w};
  float sh[8] = {sh0.x,sh0.y,sh0.z,sh0.w,sh1.x,sh1.y,sh1.z,sh1.w};
  bf16x8 o;
#pragma unroll
  for (int e = 0; e < 8; ++e) {
    float hv = (xe[e] - mu) * rstd * gg[e] + ee[e];
    float res = hv * (1.f + sc[e]) + sh[e];
    o[e] = (short)f2bf(res);
  }
  *(bf16x8*)(out + (size_t)r * 512 + c) = o;
}

// ---------------- bf16 MFMA GEMM: C[M,N] = A[M,K] @ Bw[N,K]^T ----------------
// BM: square tile edge (64 or 128). 4 waves in 2x2; F = BM/32 frags per dim per wave.
// MODE 0: bf16 out, scale cols<512 by qscale (fused QKV)
// MODE 1: f32 out = acc + cb[col] + add_[row,col]   (WO residual / FFN2 residual)
// MODE 2: bf16 out = gelu_exact(acc + cb[col])       (FFN1)
template<int MODE, int BM>
__global__ __launch_bounds__(256) void k_gemm(
    const u16* __restrict__ A, const u16* __restrict__ Bw,
    int M, int N, int K,
    u16* __restrict__ obf, float* __restrict__ of,
    const float* __restrict__ cb, const float* __restrict__ add_,
    float qscale) {
  constexpr int F = BM / 32;
  constexpr int WSUB = BM / 2;
  __shared__ u16 la[BM * 64];
  __shared__ u16 lb[BM * 64];
  const int tid = threadIdx.x;
  const int l = tid & 63, w = tid >> 6;
  const int wr = w >> 1, wc = w & 1;
  const int m0 = blockIdx.y * BM, n0 = blockIdx.x * BM;
  f32x4 acc[F][F];
  const f32x4 fz = {0.f, 0.f, 0.f, 0.f};
#pragma unroll
  for (int m = 0; m < F; ++m)
#pragma unroll
    for (int n = 0; n < F; ++n) acc[m][n] = fz;
  const int nkt = K >> 6;
  for (int kt = 0; kt < nkt; ++kt) {
    const int k0 = kt * 64;
    __syncthreads();
#pragma unroll
    for (int r2 = 0; r2 < BM / 32; ++r2) {
      unsigned e = r2 * 256 + tid;
      gload_lds16(A  + (size_t)(m0 + (e >> 3)) * K + k0 + (e & 7) * 8, la + (e & ~63u) * 8);
      gload_lds16(Bw + (size_t)(n0 + (e >> 3)) * K + k0 + (e & 7) * 8, lb + (e & ~63u) * 8);
    }
    __syncthreads();
#pragma unroll
    for (int kk = 0; kk < 2; ++kk) {
      bf16x8 af[F], bfr[F];
#pragma unroll
      for (int m = 0; m < F; ++m)
        af[m] = *(const bf16x8*)(la + (wr * WSUB + m * 16 + (l & 15)) * 64 + kk * 32 + (l >> 4) * 8);
#pragma unroll
      for (int n = 0; n < F; ++n)
        bfr[n] = *(const bf16x8*)(lb + (wc * WSUB + n * 16 + (l & 15)) * 64 + kk * 32 + (l >> 4) * 8);
#pragma unroll
      for (int m = 0; m < F; ++m)
#pragma unroll
        for (int n = 0; n < F; ++n)
          acc[m][n] = __builtin_amdgcn_mfma_f32_16x16x32_bf16(af[m], bfr[n], acc[m][n], 0, 0, 0);
    }
  }
  const int rb  = m0 + wr * WSUB + ((l >> 4) * 4);
  const int cb0 = n0 + wc * WSUB + (l & 15);
#pragma unroll
  for (int m = 0; m < F; ++m)
#pragma unroll
    for (int n = 0; n < F; ++n) {
      int gcol = cb0 + n * 16;
#pragma unroll
      for (int j = 0; j < 4; ++j) {
        int grow = rb + m * 16 + j;
        float v = acc[m][n][j];
        if (MODE == 0) {
          float scv = (gcol < 512) ? qscale : 1.f;
          obf[(size_t)grow * N + gcol] = f2bf(v * scv);
        } else if (MODE == 1) {
          of[(size_t)grow * N + gcol] = v + cb[gcol] + add_[(size_t)grow * N + gcol];
        } else {
          float t = v + cb[gcol];
          float ge = 0.5f * t * (1.f + erff(t * 0.70710678118654752f));
          obf[(size_t)grow * N + gcol] = f2bf(ge);
        }
      }
    }
}

// ---------------- pair bias via MFMA: bias[b,h,i,j] = sum_c pair[b,i,j,c]*wp[h,c] ----------------
// A = pair rows (m = flat (b,i,j), K=64 c), B = wp (n = 16 heads). Streaming, no cache reuse needed.
__global__ __launch_bounds__(256) void k_bias(const float* __restrict__ pair,
    const float* __restrict__ wp, u16* __restrict__ bias) {
  const int tid = threadIdx.x, l = tid & 63, w = tid >> 6;
  // B-frags: lane: n=h=l&15, k=c=kk*32+(l>>4)*8+e
  bf16x8 bfrag[2];
  {
    const float* wb = wp + (l & 15) * 64 + (l >> 4) * 8;
#pragma unroll
    for (int kk = 0; kk < 2; ++kk) {
      float4 w0 = *(const float4*)(wb + kk * 32);
      float4 w1 = *(const float4*)(wb + kk * 32 + 4);
      bf16x8 bb;
      bb[0] = (short)f2bf(w0.x); bb[1] = (short)f2bf(w0.y);
      bb[2] = (short)f2bf(w0.z); bb[3] = (short)f2bf(w0.w);
      bb[4] = (short)f2bf(w1.x); bb[5] = (short)f2bf(w1.y);
      bb[6] = (short)f2bf(w1.z); bb[7] = (short)f2bf(w1.w);
      bfrag[kk] = bb;
    }
  }
  const size_t m_base = (size_t)blockIdx.x * 1024 + w * 256;   // 1024 positions per block
  const f32x4 fz = {0.f, 0.f, 0.f, 0.f};
#pragma unroll 4
  for (int f = 0; f < 16; ++f) {
    size_t row = m_base + f * 16 + (l & 15);
    const float* pr = pair + row * 64 + (l >> 4) * 8;
    float4 p0 = *(const float4*)(pr);
    float4 p1 = *(const float4*)(pr + 4);
    float4 p2 = *(const float4*)(pr + 32);
    float4 p3 = *(const float4*)(pr + 36);
    bf16x8 a0, a1;
    a0[0] = (short)f2bf(p0.x); a0[1] = (short)f2bf(p0.y);
    a0[2] = (short)f2bf(p0.z); a0[3] = (short)f2bf(p0.w);
    a0[4] = (short)f2bf(p1.x); a0[5] = (short)f2bf(p1.y);
    a0[6] = (short)f2bf(p1.z); a0[7] = (short)f2bf(p1.w);
    a1[0] = (short)f2bf(p2.x); a1[1] = (short)f2bf(p2.y);
    a1[2] = (short)f2bf(p2.z); a1[3] = (short)f2bf(p2.w);
    a1[4] = (short)f2bf(p3.x); a1[5] = (short)f2bf(p3.y);
    a1[6] = (short)f2bf(p3.z); a1[7] = (short)f2bf(p3.w);
    f32x4 acc = __builtin_amdgcn_mfma_f32_16x16x32_bf16(a0, bfrag[0], fz, 0, 0, 0);
    acc = __builtin_amdgcn_mfma_f32_16x16x32_bf16(a1, bfrag[1], acc, 0, 0, 0);
    // C-frag: col = h = l&15, rows m0c..m0c+3 contiguous
    size_t m0c = m_base + f * 16 + (l >> 4) * 4;
    size_t b = m0c >> 20;
    size_t ij = m0c & 1048575;
    u16* dst = bias + (((b << 4) + (l & 15)) << 20) + ij;
    s16x4 ov;
    ov[0] = (short)f2bf(acc[0]); ov[1] = (short)f2bf(acc[1]);
    ov[2] = (short)f2bf(acc[2]); ov[3] = (short)f2bf(acc[3]);
    *(s16x4*)dst = ov;
  }
}

// ---------------- flash attention with additive bias; one block per (b,h,i-tile64) ----------------
// LDS swizzle: element (row,col) of the 64-col tiles stored at col ^ ((row&7)<<3)
// (or (d,j): j ^ ((d&7)<<3)) -> conflict-free b128 reads.
__global__ __launch_bounds__(256) void k_attn(const u16* __restrict__ qkv,
    const u16* __restrict__ bias, u16* __restrict__ ob) {
  __shared__ u16 ql[64 * 32];
  __shared__ u16 kl[64 * 32];
  __shared__ u16 vt[32 * 64];     // V transposed [d][j], j-swizzled
  __shared__ u16 bl[64 * 64];     // bias tile [i][j], j-swizzled
  __shared__ u16 pl[4 * 16 * 64]; // per-wave P [16][64], j-swizzled
  const int tid = threadIdx.x, l = tid & 63, w = tid >> 6;
  const int i0 = blockIdx.x * 64;
  const int h  = blockIdx.y;
  const int b  = blockIdx.z;
  const u16* base = qkv + (size_t)b * 1024 * 1536 + h * 32;
  {
    int row = tid >> 2, d8 = (tid & 3) * 8;
    *(bf16x8*)(ql + row * 32 + d8) = *(const bf16x8*)(base + (size_t)(i0 + row) * 1536 + d8);
  }
  __syncthreads();
  const bf16x8 aq = *(const bf16x8*)(ql + (w * 16 + (l & 15)) * 32 + (l >> 4) * 8);
  float mrun[4], lrun[4];
  f32x4 oa[2];
  const f32x4 fz = {0.f, 0.f, 0.f, 0.f};
#pragma unroll
  for (int r = 0; r < 4; ++r) { mrun[r] = -1e30f; lrun[r] = 0.f; }
  oa[0] = fz; oa[1] = fz;
  const size_t bbase = ((size_t)(b * 16 + h) * 1024 + (size_t)i0) * 1024;
  for (int jt = 0; jt < 16; ++jt) {
    const int j0 = jt * 64;
    __syncthreads();    // prev iter's QK/PV reads of kl/vt/bl complete
    {
      int row = tid >> 2, d8 = (tid & 3) * 8;
      *(bf16x8*)(kl + row * 32 + d8) = *(const bf16x8*)(base + 512 + (size_t)(j0 + row) * 1536 + d8);
      bf16x8 vv = *(const bf16x8*)(base + 1024 + (size_t)(j0 + row) * 1536 + d8);
#pragma unroll
      for (int e = 0; e < 8; ++e)
        vt[(d8 + e) * 64 + (row ^ (e << 3))] = (u16)vv[e];
      int il = tid >> 2, jl = (tid & 3) * 16;
      int v_ = (il & 7) << 3;
      const u16* bs = bias + bbase + (size_t)il * 1024 + j0 + jl;
      *(bf16x8*)(bl + il * 64 + (jl ^ v_))       = *(const bf16x8*)bs;
      *(bf16x8*)(bl + il * 64 + ((jl + 8) ^ v_)) = *(const bf16x8*)(bs + 8);
    }
    __syncthreads();
    f32x4 s[4];
#pragma unroll
    for (int n = 0; n < 4; ++n) {
      bf16x8 bk = *(const bf16x8*)(kl + (n * 16 + (l & 15)) * 32 + (l >> 4) * 8);
      s[n] = __builtin_amdgcn_mfma_f32_16x16x32_bf16(aq, bk, fz, 0, 0, 0);
    }
#pragma unroll
    for (int n = 0; n < 4; ++n)
#pragma unroll
      for (int r = 0; r < 4; ++r) {
        int row = w * 16 + (l >> 4) * 4 + r;
        int col = n * 16 + (l & 15);
        s[n][r] += bf2f(bl[row * 64 + (col ^ ((row & 7) << 3))]);
      }
    float p[4][4];
#pragma unroll
    for (int r = 0; r < 4; ++r) {
      float rm = fmaxf(fmaxf(s[0][r], s[1][r]), fmaxf(s[2][r], s[3][r]));
      rm = fmaxf(rm, __shfl_xor(rm, 1));
      rm = fmaxf(rm, __shfl_xor(rm, 2));
      rm = fmaxf(rm, __shfl_xor(rm, 4));
      rm = fmaxf(rm, __shfl_xor(rm, 8));
      float mn = fmaxf(mrun[r], rm);
      float corr = __expf(mrun[r] - mn);
      float rs = 0.f;
#pragma unroll
      for (int n = 0; n < 4; ++n) { p[n][r] = __expf(s[n][r] - mn); rs += p[n][r]; }
      rs += __shfl_xor(rs, 1); rs += __shfl_xor(rs, 2);
      rs += __shfl_xor(rs, 4); rs += __shfl_xor(rs, 8);
      lrun[r] = lrun[r] * corr + rs;
      mrun[r] = mn;
      oa[0][r] *= corr; oa[1][r] *= corr;
    }
#pragma unroll
    for (int n = 0; n < 4; ++n)
#pragma unroll
      for (int r = 0; r < 4; ++r) {
        int row = (l >> 4) * 4 + r;
        int col = n * 16 + (l & 15);
        pl[w * 1024 + row * 64 + (col ^ ((row & 7) << 3))] = f2bf(p[n][r]);
      }
    // pl is wave-private: no barrier needed (lgkmcnt ordering within wave)
#pragma unroll
    for (int kk = 0; kk < 2; ++kk) {
      int rowp = l & 15;
      bf16x8 pa = *(const bf16x8*)(pl + w * 1024 + rowp * 64 +
                    ((kk * 32 + (l >> 4) * 8) ^ ((rowp & 7) << 3)));
#pragma unroll
      for (int n = 0; n < 2; ++n) {
        int dp = n * 16 + (l & 15);
        bf16x8 vb = *(const bf16x8*)(vt + dp * 64 +
                      ((kk * 32 + (l >> 4) * 8) ^ ((dp & 7) << 3)));
        oa[n] = __builtin_amdgcn_mfma_f32_16x16x32_bf16(pa, vb, oa[n], 0, 0, 0);
      }
    }
  }
#pragma unroll
  for (int n = 0; n < 2; ++n)
#pragma unroll
    for (int r = 0; r < 4; ++r) {
      float v = oa[n][r] / lrun[r];
      ob[(size_t)(b * 1024 + i0 + w * 16 + (l >> 4) * 4 + r) * 512 + h * 32 + n * 16 + (l & 15)] = f2bf(v);
    }
}

extern "C" void kernel_launch(void* const* d_in, const int* in_sizes, int n_in,
                              void* d_out, int out_size, void* d_ws, size_t ws_size,
                              hipStream_t stream) {
  const float* x    = (const float*)d_in[0];
  const float* pair = (const float*)d_in[1];
  const float* tc   = (const float*)d_in[2];
  const float* ln1g = (const float*)d_in[3];
  const float* ln1b = (const float*)d_in[4];
  const float* a1w  = (const float*)d_in[5];
  const float* a1b  = (const float*)d_in[6];
  const float* wq   = (const float*)d_in[7];
  const float* wk   = (const float*)d_in[8];
  const float* wv   = (const float*)d_in[9];
  const float* wp   = (const float*)d_in[10];
  const float* wo   = (const float*)d_in[11];
  const float* bo   = (const float*)d_in[12];
  const float* ln2g = (const float*)d_in[13];
  const float* ln2b = (const float*)d_in[14];
  const float* a2w  = (const float*)d_in[15];
  const float* a2b  = (const float*)d_in[16];
  const float* w1   = (const float*)d_in[17];
  const float* b1   = (const float*)d_in[18];
  const float* w2   = (const float*)d_in[19];
  const float* b2   = (const float*)d_in[20];
  float* out = (float*)d_out;

  char* ws = (char*)d_ws;
  size_t off = 0;
  auto alloc = [&](size_t bytes) {
    size_t cur = off;
    off += (bytes + 255) & ~(size_t)255;
    return (void*)(ws + cur);
  };
  float* ss1    = (float*)alloc(2 * 1024 * 4);
  float* ss2    = (float*)alloc(2 * 1024 * 4);
  u16*   qkvw   = (u16*)alloc((size_t)1536 * 512 * 2);
  u16*   wo_bf  = (u16*)alloc((size_t)512 * 512 * 2);
  u16*   w1_bf  = (u16*)alloc((size_t)2048 * 512 * 2);
  u16*   w2_bf  = (u16*)alloc((size_t)512 * 2048 * 2);
  u16*   h_bf   = (u16*)alloc((size_t)2048 * 512 * 2);
  u16*   qkv_bf = (u16*)alloc((size_t)2048 * 1536 * 2);
  u16*   o_bf   = (u16*)alloc((size_t)2048 * 512 * 2);
  u16*   h2_bf  = (u16*)alloc((size_t)2048 * 512 * 2);
  float* xmid   = (float*)alloc((size_t)2048 * 512 * 4);
  u16*   mid_bf = (u16*)alloc((size_t)2048 * 2048 * 2);
  u16*   bias_bf= (u16*)alloc((size_t)2 * 16 * 1024 * 1024 * 2);
  (void)ws_size; (void)in_sizes; (void)n_in; (void)out_size;

  // all weights -> bf16 in one launch
  k_cvt_all<<<3072, 256, 0, stream>>>(wq, wk, wv, wo, w1, w2,
                                      qkvw, wo_bf, w1_bf, w2_bf);

  // adaLN scale/shift for both blocks
  k_ss<<<1024, 256, 0, stream>>>(tc, a1w, a1b, a2w, a2b, ss1, ss2);

  // adaLN1 -> h (bf16)
  k_adaln<<<512, 256, 0, stream>>>(x, ln1g, ln1b, ss1, h_bf);

  // fused QKV GEMM: [2048,512]x[1536,512]^T (q pre-scaled by 1/sqrt(32)); 64x64 tiles
  k_gemm<0, 64><<<dim3(24, 32), 256, 0, stream>>>(h_bf, qkvw, 2048, 1536, 512,
      qkv_bf, nullptr, nullptr, nullptr, 0.17677669529663687f);

  // pair bias via MFMA -> bf16 [B,H,L,L]
  k_bias<<<2048, 256, 0, stream>>>(pair, wp, bias_bf);

  // flash attention
  k_attn<<<dim3(16, 16, 2), 256, 0, stream>>>(qkv_bf, bias_bf, o_bf);

  // out proj + residual: xmid = x + O@wo^T + bo (f32); 64x64 tiles
  k_gemm<1, 64><<<dim3(8, 32), 256, 0, stream>>>(o_bf, wo_bf, 2048, 512, 512,
      nullptr, xmid, bo, x, 1.f);

  // adaLN2 -> h2 (bf16)
  k_adaln<<<512, 256, 0, stream>>>(xmid, ln2g, ln2b, ss2, h2_bf);

  // FFN1 + exact GELU -> mid (bf16); 128x128 tiles
  k_gemm<2, 128><<<dim3(16, 16), 256, 0, stream>>>(h2_bf, w1_bf, 2048, 2048, 512,
      mid_bf, nullptr, b1, nullptr, 1.f);

  // FFN2 + residual -> out (f32); 64x64 tiles
  k_gemm<1, 64><<<dim3(8, 32), 256, 0, stream>>>(mid_bf, w2_bf, 2048, 512, 2048,
      nullptr, out, b2, xmid, 1.f);
}

// Round 3
// 275.504 us; speedup vs baseline: 1.3422x; 1.0155x over previous
//
#include <hip/hip_runtime.h>
#include <math.h>

typedef unsigned short u16;
typedef __attribute__((ext_vector_type(8))) short bf16x8;
typedef __attribute__((ext_vector_type(4))) short s16x4;
typedef __attribute__((ext_vector_type(4))) float f32x4;

__device__ __forceinline__ u16 f2bf(float f) {
  union { float f; unsigned u; } v; v.f = f;
  unsigned r = v.u + 0x7FFFu + ((v.u >> 16) & 1u);   // RNE
  return (u16)(r >> 16);
}
__device__ __forceinline__ float bf2f(u16 h) {
  union { unsigned u; float f; } v; v.u = ((unsigned)h) << 16; return v.f;
}
__device__ __forceinline__ void gload_lds16(const void* g, void* l) {
  __builtin_amdgcn_global_load_lds((const __attribute__((address_space(1))) void*)g,
                                   (__attribute__((address_space(3))) void*)l, 16, 0, 0);
}

// ---------------- merged: weight cvt (blocks 0..3071) + adaLN scale/shift (3072..4095) ----------------
__global__ __launch_bounds__(256) void k_pre(
    const float* __restrict__ wq, const float* __restrict__ wk,
    const float* __restrict__ wv, const float* __restrict__ wo,
    const float* __restrict__ w1, const float* __restrict__ w2,
    u16* __restrict__ qkvw, u16* __restrict__ wo_bf,
    u16* __restrict__ w1_bf, u16* __restrict__ w2_bf,
    const float* __restrict__ tc,
    const float* __restrict__ wa, const float* __restrict__ ba,
    const float* __restrict__ wb, const float* __restrict__ bb,
    float* __restrict__ ss1, float* __restrict__ ss2) {
  if (blockIdx.x < 3072) {
    int i = (blockIdx.x * 256 + threadIdx.x) * 4;   // element index, total 3145728
    const float* s; u16* d;
    if (i < 786432) {
      d = qkvw + i;
      if (i < 262144) s = wq + i;
      else if (i < 524288) s = wk + (i - 262144);
      else s = wv + (i - 524288);
    } else if (i < 1048576) { s = wo + (i - 786432); d = wo_bf + (i - 786432); }
    else if (i < 2097152)   { s = w1 + (i - 1048576); d = w1_bf + (i - 1048576); }
    else                    { s = w2 + (i - 2097152); d = w2_bf + (i - 2097152); }
    float4 v = *(const float4*)s;
    s16x4 o;
    o[0] = (short)f2bf(v.x); o[1] = (short)f2bf(v.y);
    o[2] = (short)f2bf(v.z); o[3] = (short)f2bf(v.w);
    *(s16x4*)d = o;
  } else {
    int wv_ = (blockIdx.x - 3072) * 4 + (threadIdx.x >> 6);   // 0..4095
    int l = threadIdx.x & 63;
    int which = wv_ >> 11;
    int rem = wv_ & 2047;
    int b = rem >> 10;
    int row = rem & 1023;
    const float* w = which ? wb : wa;
    const float4* t4 = (const float4*)(tc + b * 512);
    const float4* w4 = (const float4*)(w + (size_t)row * 512);
    float s = 0.f;
#pragma unroll
    for (int q = 0; q < 2; ++q) {
      float4 a = t4[l * 2 + q], c = w4[l * 2 + q];
      s += a.x * c.x + a.y * c.y + a.z * c.z + a.w * c.w;
    }
#pragma unroll
    for (int m = 32; m; m >>= 1) s += __shfl_xor(s, m);
    if (l == 0) {
      float bias = (which ? bb : ba)[row];
      (which ? ss2 : ss1)[b * 1024 + row] = s + bias;
    }
  }
}

// ---------------- adaLN: out = (LN(x)*g+b)*(1+scale)+shift -> bf16 ----------------
__global__ __launch_bounds__(256) void k_adaln(const float* __restrict__ x,
    const float* __restrict__ g, const float* __restrict__ be,
    const float* __restrict__ ss, u16* __restrict__ out) {
  int r = blockIdx.x * 4 + (threadIdx.x >> 6);    // row 0..2047
  int l = threadIdx.x & 63;
  int b = r >> 10;
  const float4* x4 = (const float4*)(x + (size_t)r * 512);
  float4 v0 = x4[l * 2], v1 = x4[l * 2 + 1];
  float s = v0.x + v0.y + v0.z + v0.w + v1.x + v1.y + v1.z + v1.w;
  float s2 = v0.x*v0.x + v0.y*v0.y + v0.z*v0.z + v0.w*v0.w
           + v1.x*v1.x + v1.y*v1.y + v1.z*v1.z + v1.w*v1.w;
#pragma unroll
  for (int m = 32; m; m >>= 1) { s += __shfl_xor(s, m); s2 += __shfl_xor(s2, m); }
  float mu = s * (1.f / 512.f);
  float var = s2 * (1.f / 512.f) - mu * mu;
  float rstd = rsqrtf(var + 1e-5f);
  int c = l * 8;
  float4 g0 = *(const float4*)(g + c),  g1 = *(const float4*)(g + c + 4);
  float4 e0 = *(const float4*)(be + c), e1 = *(const float4*)(be + c + 4);
  const float* sb = ss + b * 1024;
  float4 sc0 = *(const float4*)(sb + c),       sc1 = *(const float4*)(sb + c + 4);
  float4 sh0 = *(const float4*)(sb + 512 + c), sh1 = *(const float4*)(sb + 512 + c + 4);
  float xe[8] = {v0.x,v0.y,v0.z,v0.w,v1.x,v1.y,v1.z,v1.w};
  float gg[8] = {g0.x,g0.y,g0.z,g0.w,g1.x,g1.y,g1.z,g1.w};
  float ee[8] = {e0.x,e0.y,e0.z,e0.w,e1.x,e1.y,e1.z,e1.w};
  float sc[8] = {sc0.x,sc0.y,sc0.z,sc0.w,sc1.x,sc1.y,sc1.z,sc1.w};
  float sh[8] = {sh0.x,sh0.y,sh0.z,sh0.w,sh1.x,sh1.y,sh1.z,sh1.w};
  bf16x8 o;
#pragma unroll
  for (int e = 0; e < 8; ++e) {
    float hv = (xe[e] - mu) * rstd * gg[e] + ee[e];
    float res = hv * (1.f + sc[e]) + sh[e];
    o[e] = (short)f2bf(res);
  }
  *(bf16x8*)(out + (size_t)r * 512 + c) = o;
}

// ---------------- bf16 MFMA GEMM body: C[M,N] = A[M,K] @ Bw[N,K]^T, BMxBN tile ----------------
// 4 waves in 2x2. MODE 0: bf16 out, scale cols<512 by qscale. MODE 1: f32 out = acc+cb+add_.
// MODE 2: bf16 out = gelu_exact(acc+cb).
template<int MODE, int BM, int BN>
__device__ __forceinline__ void gemm_body(
    int bxn, int bxm,
    const u16* __restrict__ A, const u16* __restrict__ Bw,
    int M, int N, int K,
    u16* __restrict__ obf, float* __restrict__ of,
    const float* __restrict__ cb, const float* __restrict__ add_,
    float qscale) {
  constexpr int FM = BM / 32, FN = BN / 32;
  constexpr int WM = BM / 2,  WN = BN / 2;
  __shared__ u16 la[BM * 64];
  __shared__ u16 lb[BN * 64];
  const int tid = threadIdx.x;
  const int l = tid & 63, w = tid >> 6;
  const int wr = w >> 1, wc = w & 1;
  const int m0 = bxm * BM, n0 = bxn * BN;
  f32x4 acc[FM][FN];
  const f32x4 fz = {0.f, 0.f, 0.f, 0.f};
#pragma unroll
  for (int m = 0; m < FM; ++m)
#pragma unroll
    for (int n = 0; n < FN; ++n) acc[m][n] = fz;
  const int nkt = K >> 6;
  for (int kt = 0; kt < nkt; ++kt) {
    const int k0 = kt * 64;
    __syncthreads();
#pragma unroll
    for (int r2 = 0; r2 < BM / 32; ++r2) {
      unsigned e = r2 * 256 + tid;
      gload_lds16(A + (size_t)(m0 + (e >> 3)) * K + k0 + (e & 7) * 8, la + (e & ~63u) * 8);
    }
#pragma unroll
    for (int r2 = 0; r2 < BN / 32; ++r2) {
      unsigned e = r2 * 256 + tid;
      gload_lds16(Bw + (size_t)(n0 + (e >> 3)) * K + k0 + (e & 7) * 8, lb + (e & ~63u) * 8);
    }
    __syncthreads();
#pragma unroll
    for (int kk = 0; kk < 2; ++kk) {
      bf16x8 af[FM], bfr[FN];
#pragma unroll
      for (int m = 0; m < FM; ++m)
        af[m] = *(const bf16x8*)(la + (wr * WM + m * 16 + (l & 15)) * 64 + kk * 32 + (l >> 4) * 8);
#pragma unroll
      for (int n = 0; n < FN; ++n)
        bfr[n] = *(const bf16x8*)(lb + (wc * WN + n * 16 + (l & 15)) * 64 + kk * 32 + (l >> 4) * 8);
#pragma unroll
      for (int m = 0; m < FM; ++m)
#pragma unroll
        for (int n = 0; n < FN; ++n)
          acc[m][n] = __builtin_amdgcn_mfma_f32_16x16x32_bf16(af[m], bfr[n], acc[m][n], 0, 0, 0);
    }
  }
  const int rb  = m0 + wr * WM + ((l >> 4) * 4);
  const int cb0 = n0 + wc * WN + (l & 15);
#pragma unroll
  for (int m = 0; m < FM; ++m)
#pragma unroll
    for (int n = 0; n < FN; ++n) {
      int gcol = cb0 + n * 16;
#pragma unroll
      for (int j = 0; j < 4; ++j) {
        int grow = rb + m * 16 + j;
        float v = acc[m][n][j];
        if (MODE == 0) {
          float scv = (gcol < 512) ? qscale : 1.f;
          obf[(size_t)grow * N + gcol] = f2bf(v * scv);
        } else if (MODE == 1) {
          of[(size_t)grow * N + gcol] = v + cb[gcol] + add_[(size_t)grow * N + gcol];
        } else {
          float t = v + cb[gcol];
          float ge = 0.5f * t * (1.f + erff(t * 0.70710678118654752f));
          obf[(size_t)grow * N + gcol] = f2bf(ge);
        }
      }
    }
}

template<int MODE, int BM, int BN>
__global__ __launch_bounds__(256) void k_gemm(
    const u16* __restrict__ A, const u16* __restrict__ Bw,
    int M, int N, int K,
    u16* __restrict__ obf, float* __restrict__ of,
    const float* __restrict__ cb, const float* __restrict__ add_,
    float qscale) {
  gemm_body<MODE, BM, BN>(blockIdx.x, blockIdx.y, A, Bw, M, N, K, obf, of, cb, add_, qscale);
}

// ---------------- pair bias body: bias[b,h,i,j] = sum_c pair[b,i,j,c]*wp[h,c] ----------------
__device__ __forceinline__ void bias_body(int blk, const float* __restrict__ pair,
    const float* __restrict__ wp, u16* __restrict__ bias) {
  const int tid = threadIdx.x, l = tid & 63, w = tid >> 6;
  bf16x8 bfrag[2];
  {
    const float* wb = wp + (l & 15) * 64 + (l >> 4) * 8;
#pragma unroll
    for (int kk = 0; kk < 2; ++kk) {
      float4 w0 = *(const float4*)(wb + kk * 32);
      float4 w1 = *(const float4*)(wb + kk * 32 + 4);
      bf16x8 bb;
      bb[0] = (short)f2bf(w0.x); bb[1] = (short)f2bf(w0.y);
      bb[2] = (short)f2bf(w0.z); bb[3] = (short)f2bf(w0.w);
      bb[4] = (short)f2bf(w1.x); bb[5] = (short)f2bf(w1.y);
      bb[6] = (short)f2bf(w1.z); bb[7] = (short)f2bf(w1.w);
      bfrag[kk] = bb;
    }
  }
  const size_t m_base = (size_t)blk * 1024 + w * 256;   // 1024 positions per block
  const f32x4 fz = {0.f, 0.f, 0.f, 0.f};
#pragma unroll 4
  for (int f = 0; f < 16; ++f) {
    size_t row = m_base + f * 16 + (l & 15);
    const float* pr = pair + row * 64 + (l >> 4) * 8;
    float4 p0 = *(const float4*)(pr);
    float4 p1 = *(const float4*)(pr + 4);
    float4 p2 = *(const float4*)(pr + 32);
    float4 p3 = *(const float4*)(pr + 36);
    bf16x8 a0, a1;
    a0[0] = (short)f2bf(p0.x); a0[1] = (short)f2bf(p0.y);
    a0[2] = (short)f2bf(p0.z); a0[3] = (short)f2bf(p0.w);
    a0[4] = (short)f2bf(p1.x); a0[5] = (short)f2bf(p1.y);
    a0[6] = (short)f2bf(p1.z); a0[7] = (short)f2bf(p1.w);
    a1[0] = (short)f2bf(p2.x); a1[1] = (short)f2bf(p2.y);
    a1[2] = (short)f2bf(p2.z); a1[3] = (short)f2bf(p2.w);
    a1[4] = (short)f2bf(p3.x); a1[5] = (short)f2bf(p3.y);
    a1[6] = (short)f2bf(p3.z); a1[7] = (short)f2bf(p3.w);
    f32x4 acc = __builtin_amdgcn_mfma_f32_16x16x32_bf16(a0, bfrag[0], fz, 0, 0, 0);
    acc = __builtin_amdgcn_mfma_f32_16x16x32_bf16(a1, bfrag[1], acc, 0, 0, 0);
    size_t m0c = m_base + f * 16 + (l >> 4) * 4;
    size_t b = m0c >> 20;
    size_t ij = m0c & 1048575;
    u16* dst = bias + (((b << 4) + (l & 15)) << 20) + ij;
    s16x4 ov;
    ov[0] = (short)f2bf(acc[0]); ov[1] = (short)f2bf(acc[1]);
    ov[2] = (short)f2bf(acc[2]); ov[3] = (short)f2bf(acc[3]);
    *(s16x4*)dst = ov;
  }
}

// ---------------- mega: QKV GEMM (blocks 0..191, 128x128) ∥ pair bias (192..2239) ----------------
__global__ __launch_bounds__(256) void k_mega(
    const u16* __restrict__ h_bf, const u16* __restrict__ qkvw,
    u16* __restrict__ qkv_bf, float qscale,
    const float* __restrict__ pair, const float* __restrict__ wp,
    u16* __restrict__ bias) {
  if (blockIdx.x < 192) {
    gemm_body<0, 128, 128>(blockIdx.x % 12, blockIdx.x / 12,
        h_bf, qkvw, 2048, 1536, 512, qkv_bf, nullptr, nullptr, nullptr, qscale);
  } else {
    bias_body(blockIdx.x - 192, pair, wp, bias);
  }
}

// ---------------- flash attention with additive bias; one block per (b,h,i-tile64) ----------------
__global__ __launch_bounds__(256) void k_attn(const u16* __restrict__ qkv,
    const u16* __restrict__ bias, u16* __restrict__ ob) {
  __shared__ u16 ql[64 * 32];
  __shared__ u16 kl[64 * 32];
  __shared__ u16 vt[32 * 64];     // V transposed [d][j], j-swizzled
  __shared__ u16 bl[64 * 64];     // bias tile [i][j], j-swizzled
  __shared__ u16 pl[4 * 16 * 64]; // per-wave P [16][64], j-swizzled
  const int tid = threadIdx.x, l = tid & 63, w = tid >> 6;
  const int i0 = blockIdx.x * 64;
  const int h  = blockIdx.y;
  const int b  = blockIdx.z;
  const u16* base = qkv + (size_t)b * 1024 * 1536 + h * 32;
  {
    int row = tid >> 2, d8 = (tid & 3) * 8;
    *(bf16x8*)(ql + row * 32 + d8) = *(const bf16x8*)(base + (size_t)(i0 + row) * 1536 + d8);
  }
  __syncthreads();
  const bf16x8 aq = *(const bf16x8*)(ql + (w * 16 + (l & 15)) * 32 + (l >> 4) * 8);
  float mrun[4], lrun[4];
  f32x4 oa[2];
  const f32x4 fz = {0.f, 0.f, 0.f, 0.f};
#pragma unroll
  for (int r = 0; r < 4; ++r) { mrun[r] = -1e30f; lrun[r] = 0.f; }
  oa[0] = fz; oa[1] = fz;
  const size_t bbase = ((size_t)(b * 16 + h) * 1024 + (size_t)i0) * 1024;
  for (int jt = 0; jt < 16; ++jt) {
    const int j0 = jt * 64;
    __syncthreads();    // prev iter's QK/PV reads of kl/vt/bl complete
    {
      int row = tid >> 2, d8 = (tid & 3) * 8;
      *(bf16x8*)(kl + row * 32 + d8) = *(const bf16x8*)(base + 512 + (size_t)(j0 + row) * 1536 + d8);
      bf16x8 vv = *(const bf16x8*)(base + 1024 + (size_t)(j0 + row) * 1536 + d8);
#pragma unroll
      for (int e = 0; e < 8; ++e)
        vt[(d8 + e) * 64 + (row ^ (e << 3))] = (u16)vv[e];
      int il = tid >> 2, jl = (tid & 3) * 16;
      int v_ = (il & 7) << 3;
      const u16* bs = bias + bbase + (size_t)il * 1024 + j0 + jl;
      *(bf16x8*)(bl + il * 64 + (jl ^ v_))       = *(const bf16x8*)bs;
      *(bf16x8*)(bl + il * 64 + ((jl + 8) ^ v_)) = *(const bf16x8*)(bs + 8);
    }
    __syncthreads();
    f32x4 s[4];
#pragma unroll
    for (int n = 0; n < 4; ++n) {
      bf16x8 bk = *(const bf16x8*)(kl + (n * 16 + (l & 15)) * 32 + (l >> 4) * 8);
      s[n] = __builtin_amdgcn_mfma_f32_16x16x32_bf16(aq, bk, fz, 0, 0, 0);
    }
#pragma unroll
    for (int n = 0; n < 4; ++n)
#pragma unroll
      for (int r = 0; r < 4; ++r) {
        int row = w * 16 + (l >> 4) * 4 + r;
        int col = n * 16 + (l & 15);
        s[n][r] += bf2f(bl[row * 64 + (col ^ ((row & 7) << 3))]);
      }
    float p[4][4];
#pragma unroll
    for (int r = 0; r < 4; ++r) {
      float rm = fmaxf(fmaxf(s[0][r], s[1][r]), fmaxf(s[2][r], s[3][r]));
      rm = fmaxf(rm, __shfl_xor(rm, 1));
      rm = fmaxf(rm, __shfl_xor(rm, 2));
      rm = fmaxf(rm, __shfl_xor(rm, 4));
      rm = fmaxf(rm, __shfl_xor(rm, 8));
      float mn = fmaxf(mrun[r], rm);
      float corr = __expf(mrun[r] - mn);
      float rs = 0.f;
#pragma unroll
      for (int n = 0; n < 4; ++n) { p[n][r] = __expf(s[n][r] - mn); rs += p[n][r]; }
      rs += __shfl_xor(rs, 1); rs += __shfl_xor(rs, 2);
      rs += __shfl_xor(rs, 4); rs += __shfl_xor(rs, 8);
      lrun[r] = lrun[r] * corr + rs;
      mrun[r] = mn;
      oa[0][r] *= corr; oa[1][r] *= corr;
    }
#pragma unroll
    for (int n = 0; n < 4; ++n)
#pragma unroll
      for (int r = 0; r < 4; ++r) {
        int row = (l >> 4) * 4 + r;
        int col = n * 16 + (l & 15);
        pl[w * 1024 + row * 64 + (col ^ ((row & 7) << 3))] = f2bf(p[n][r]);
      }
    // pl is wave-private: no barrier needed (lgkmcnt ordering within wave)
#pragma unroll
    for (int kk = 0; kk < 2; ++kk) {
      int rowp = l & 15;
      bf16x8 pa = *(const bf16x8*)(pl + w * 1024 + rowp * 64 +
                    ((kk * 32 + (l >> 4) * 8) ^ ((rowp & 7) << 3)));
#pragma unroll
      for (int n = 0; n < 2; ++n) {
        int dp = n * 16 + (l & 15);
        bf16x8 vb = *(const bf16x8*)(vt + dp * 64 +
                      ((kk * 32 + (l >> 4) * 8) ^ ((dp & 7) << 3)));
        oa[n] = __builtin_amdgcn_mfma_f32_16x16x32_bf16(pa, vb, oa[n], 0, 0, 0);
      }
    }
  }
#pragma unroll
  for (int n = 0; n < 2; ++n)
#pragma unroll
    for (int r = 0; r < 4; ++r) {
      float v = oa[n][r] / lrun[r];
      ob[(size_t)(b * 1024 + i0 + w * 16 + (l >> 4) * 4 + r) * 512 + h * 32 + n * 16 + (l & 15)] = f2bf(v);
    }
}

extern "C" void kernel_launch(void* const* d_in, const int* in_sizes, int n_in,
                              void* d_out, int out_size, void* d_ws, size_t ws_size,
                              hipStream_t stream) {
  const float* x    = (const float*)d_in[0];
  const float* pair = (const float*)d_in[1];
  const float* tc   = (const float*)d_in[2];
  const float* ln1g = (const float*)d_in[3];
  const float* ln1b = (const float*)d_in[4];
  const float* a1w  = (const float*)d_in[5];
  const float* a1b  = (const float*)d_in[6];
  const float* wq   = (const float*)d_in[7];
  const float* wk   = (const float*)d_in[8];
  const float* wv   = (const float*)d_in[9];
  const float* wp   = (const float*)d_in[10];
  const float* wo   = (const float*)d_in[11];
  const float* bo   = (const float*)d_in[12];
  const float* ln2g = (const float*)d_in[13];
  const float* ln2b = (const float*)d_in[14];
  const float* a2w  = (const float*)d_in[15];
  const float* a2b  = (const float*)d_in[16];
  const float* w1   = (const float*)d_in[17];
  const float* b1   = (const float*)d_in[18];
  const float* w2   = (const float*)d_in[19];
  const float* b2   = (const float*)d_in[20];
  float* out = (float*)d_out;

  char* ws = (char*)d_ws;
  size_t off = 0;
  auto alloc = [&](size_t bytes) {
    size_t cur = off;
    off += (bytes + 255) & ~(size_t)255;
    return (void*)(ws + cur);
  };
  float* ss1    = (float*)alloc(2 * 1024 * 4);
  float* ss2    = (float*)alloc(2 * 1024 * 4);
  u16*   qkvw   = (u16*)alloc((size_t)1536 * 512 * 2);
  u16*   wo_bf  = (u16*)alloc((size_t)512 * 512 * 2);
  u16*   w1_bf  = (u16*)alloc((size_t)2048 * 512 * 2);
  u16*   w2_bf  = (u16*)alloc((size_t)512 * 2048 * 2);
  u16*   h_bf   = (u16*)alloc((size_t)2048 * 512 * 2);
  u16*   qkv_bf = (u16*)alloc((size_t)2048 * 1536 * 2);
  u16*   o_bf   = (u16*)alloc((size_t)2048 * 512 * 2);
  u16*   h2_bf  = (u16*)alloc((size_t)2048 * 512 * 2);
  float* xmid   = (float*)alloc((size_t)2048 * 512 * 4);
  u16*   mid_bf = (u16*)alloc((size_t)2048 * 2048 * 2);
  u16*   bias_bf= (u16*)alloc((size_t)2 * 16 * 1024 * 1024 * 2);
  (void)ws_size; (void)in_sizes; (void)n_in; (void)out_size;

  // weights -> bf16 + adaLN scale/shift, one launch
  k_pre<<<4096, 256, 0, stream>>>(wq, wk, wv, wo, w1, w2,
                                  qkvw, wo_bf, w1_bf, w2_bf,
                                  tc, a1w, a1b, a2w, a2b, ss1, ss2);

  // adaLN1 -> h (bf16)
  k_adaln<<<512, 256, 0, stream>>>(x, ln1g, ln1b, ss1, h_bf);

  // QKV GEMM (192 blocks, 128x128) ∥ pair bias (2048 blocks) in one dispatch
  k_mega<<<2240, 256, 0, stream>>>(h_bf, qkvw, qkv_bf, 0.17677669529663687f,
                                   pair, wp, bias_bf);

  // flash attention
  k_attn<<<dim3(16, 16, 2), 256, 0, stream>>>(qkv_bf, bias_bf, o_bf);

  // out proj + residual: xmid = x + O@wo^T + bo (f32); 64x64 tiles
  k_gemm<1, 64, 64><<<dim3(8, 32), 256, 0, stream>>>(o_bf, wo_bf, 2048, 512, 512,
      nullptr, xmid, bo, x, 1.f);

  // adaLN2 -> h2 (bf16)
  k_adaln<<<512, 256, 0, stream>>>(xmid, ln2g, ln2b, ss2, h2_bf);

  // FFN1 + exact GELU -> mid (bf16); 128x128 tiles
  k_gemm<2, 128, 128><<<dim3(16, 16), 256, 0, stream>>>(h2_bf, w1_bf, 2048, 2048, 512,
      mid_bf, nullptr, b1, nullptr, 1.f);

  // FFN2 + residual -> out (f32); 64x64 tiles
  k_gemm<1, 64, 64><<<dim3(8, 32), 256, 0, stream>>>(mid_bf, w2_bf, 2048, 512, 2048,
      nullptr, out, b2, xmid, 1.f);
}

// Round 4
// 238.541 us; speedup vs baseline: 1.5501x; 1.1550x over previous
//
#include <hip/hip_runtime.h>
#include <math.h>

typedef unsigned short u16;
typedef __attribute__((ext_vector_type(8))) short bf16x8;
typedef __attribute__((ext_vector_type(4))) short s16x4;
typedef __attribute__((ext_vector_type(4))) float f32x4;

__device__ __forceinline__ u16 f2bf(float f) {
  union { float f; unsigned u; } v; v.f = f;
  unsigned r = v.u + 0x7FFFu + ((v.u >> 16) & 1u);   // RNE
  return (u16)(r >> 16);
}
__device__ __forceinline__ float bf2f(u16 h) {
  union { unsigned u; float f; } v; v.u = ((unsigned)h) << 16; return v.f;
}
__device__ __forceinline__ void gload_lds16(const void* g, void* l) {
  __builtin_amdgcn_global_load_lds((const __attribute__((address_space(1))) void*)g,
                                   (__attribute__((address_space(3))) void*)l, 16, 0, 0);
}

// ---------------- merged: weight cvt (blocks 0..3071) + adaLN scale/shift (3072..4095) ----------------
__global__ __launch_bounds__(256) void k_pre(
    const float* __restrict__ wq, const float* __restrict__ wk,
    const float* __restrict__ wv, const float* __restrict__ wo,
    const float* __restrict__ w1, const float* __restrict__ w2,
    u16* __restrict__ qkvw, u16* __restrict__ wo_bf,
    u16* __restrict__ w1_bf, u16* __restrict__ w2_bf,
    const float* __restrict__ tc,
    const float* __restrict__ wa, const float* __restrict__ ba,
    const float* __restrict__ wb, const float* __restrict__ bb,
    float* __restrict__ ss1, float* __restrict__ ss2) {
  if (blockIdx.x < 3072) {
    int i = (blockIdx.x * 256 + threadIdx.x) * 4;   // element index, total 3145728
    const float* s; u16* d;
    if (i < 786432) {
      d = qkvw + i;
      if (i < 262144) s = wq + i;
      else if (i < 524288) s = wk + (i - 262144);
      else s = wv + (i - 524288);
    } else if (i < 1048576) { s = wo + (i - 786432); d = wo_bf + (i - 786432); }
    else if (i < 2097152)   { s = w1 + (i - 1048576); d = w1_bf + (i - 1048576); }
    else                    { s = w2 + (i - 2097152); d = w2_bf + (i - 2097152); }
    float4 v = *(const float4*)s;
    s16x4 o;
    o[0] = (short)f2bf(v.x); o[1] = (short)f2bf(v.y);
    o[2] = (short)f2bf(v.z); o[3] = (short)f2bf(v.w);
    *(s16x4*)d = o;
  } else {
    int wv_ = (blockIdx.x - 3072) * 4 + (threadIdx.x >> 6);   // 0..4095
    int l = threadIdx.x & 63;
    int which = wv_ >> 11;
    int rem = wv_ & 2047;
    int b = rem >> 10;
    int row = rem & 1023;
    const float* w = which ? wb : wa;
    const float4* t4 = (const float4*)(tc + b * 512);
    const float4* w4 = (const float4*)(w + (size_t)row * 512);
    float s = 0.f;
#pragma unroll
    for (int q = 0; q < 2; ++q) {
      float4 a = t4[l * 2 + q], c = w4[l * 2 + q];
      s += a.x * c.x + a.y * c.y + a.z * c.z + a.w * c.w;
    }
#pragma unroll
    for (int m = 32; m; m >>= 1) s += __shfl_xor(s, m);
    if (l == 0) {
      float bias = (which ? bb : ba)[row];
      (which ? ss2 : ss1)[b * 1024 + row] = s + bias;
    }
  }
}

// ---------------- adaLN: out = (LN(x)*g+b)*(1+scale)+shift -> bf16 ----------------
__global__ __launch_bounds__(256) void k_adaln(const float* __restrict__ x,
    const float* __restrict__ g, const float* __restrict__ be,
    const float* __restrict__ ss, u16* __restrict__ out) {
  int r = blockIdx.x * 4 + (threadIdx.x >> 6);    // row 0..2047
  int l = threadIdx.x & 63;
  int b = r >> 10;
  const float4* x4 = (const float4*)(x + (size_t)r * 512);
  float4 v0 = x4[l * 2], v1 = x4[l * 2 + 1];
  float s = v0.x + v0.y + v0.z + v0.w + v1.x + v1.y + v1.z + v1.w;
  float s2 = v0.x*v0.x + v0.y*v0.y + v0.z*v0.z + v0.w*v0.w
           + v1.x*v1.x + v1.y*v1.y + v1.z*v1.z + v1.w*v1.w;
#pragma unroll
  for (int m = 32; m; m >>= 1) { s += __shfl_xor(s, m); s2 += __shfl_xor(s2, m); }
  float mu = s * (1.f / 512.f);
  float var = s2 * (1.f / 512.f) - mu * mu;
  float rstd = rsqrtf(var + 1e-5f);
  int c = l * 8;
  float4 g0 = *(const float4*)(g + c),  g1 = *(const float4*)(g + c + 4);
  float4 e0 = *(const float4*)(be + c), e1 = *(const float4*)(be + c + 4);
  const float* sb = ss + b * 1024;
  float4 sc0 = *(const float4*)(sb + c),       sc1 = *(const float4*)(sb + c + 4);
  float4 sh0 = *(const float4*)(sb + 512 + c), sh1 = *(const float4*)(sb + 512 + c + 4);
  float xe[8] = {v0.x,v0.y,v0.z,v0.w,v1.x,v1.y,v1.z,v1.w};
  float gg[8] = {g0.x,g0.y,g0.z,g0.w,g1.x,g1.y,g1.z,g1.w};
  float ee[8] = {e0.x,e0.y,e0.z,e0.w,e1.x,e1.y,e1.z,e1.w};
  float sc[8] = {sc0.x,sc0.y,sc0.z,sc0.w,sc1.x,sc1.y,sc1.z,sc1.w};
  float sh[8] = {sh0.x,sh0.y,sh0.z,sh0.w,sh1.x,sh1.y,sh1.z,sh1.w};
  bf16x8 o;
#pragma unroll
  for (int e = 0; e < 8; ++e) {
    float hv = (xe[e] - mu) * rstd * gg[e] + ee[e];
    float res = hv * (1.f + sc[e]) + sh[e];
    o[e] = (short)f2bf(res);
  }
  *(bf16x8*)(out + (size_t)r * 512 + c) = o;
}

// ---------------- bf16 MFMA GEMM body: C[M,N] = A[M,K] @ Bw[N,K]^T, BMxBN tile ----------------
// LDS holds XOR-swizzled tiles: LDS[row][chunk] = global[row][chunk ^ (row&7)] (16B chunks),
// achieved by pre-swizzling the global source (global_load_lds dest must stay linear).
// Reads apply the same XOR -> <=2-way bank conflicts (free).
template<int MODE, int BM, int BN>
__device__ __forceinline__ void gemm_body(
    int bxn, int bxm,
    const u16* __restrict__ A, const u16* __restrict__ Bw,
    int M, int N, int K,
    u16* __restrict__ obf, float* __restrict__ of,
    const float* __restrict__ cb, const float* __restrict__ add_,
    float qscale) {
  constexpr int FM = BM / 32, FN = BN / 32;
  constexpr int WM = BM / 2,  WN = BN / 2;
  __shared__ u16 la[BM * 64];
  __shared__ u16 lb[BN * 64];
  const int tid = threadIdx.x;
  const int l = tid & 63, w = tid >> 6;
  const int wr = w >> 1, wc = w & 1;
  const int m0 = bxm * BM, n0 = bxn * BN;
  f32x4 acc[FM][FN];
  const f32x4 fz = {0.f, 0.f, 0.f, 0.f};
#pragma unroll
  for (int m = 0; m < FM; ++m)
#pragma unroll
    for (int n = 0; n < FN; ++n) acc[m][n] = fz;
  const int nkt = K >> 6;
  for (int kt = 0; kt < nkt; ++kt) {
    const int k0 = kt * 64;
    __syncthreads();
#pragma unroll
    for (int r2 = 0; r2 < BM / 32; ++r2) {
      unsigned e = r2 * 256 + tid;
      unsigned row = e >> 3, ch = (e & 7) ^ (row & 7);
      gload_lds16(A + (size_t)(m0 + row) * K + k0 + ch * 8, la + (e & ~63u) * 8);
    }
#pragma unroll
    for (int r2 = 0; r2 < BN / 32; ++r2) {
      unsigned e = r2 * 256 + tid;
      unsigned row = e >> 3, ch = (e & 7) ^ (row & 7);
      gload_lds16(Bw + (size_t)(n0 + row) * K + k0 + ch * 8, lb + (e & ~63u) * 8);
    }
    __syncthreads();
#pragma unroll
    for (int kk = 0; kk < 2; ++kk) {
      bf16x8 af[FM], bfr[FN];
#pragma unroll
      for (int m = 0; m < FM; ++m) {
        int R = wr * WM + m * 16 + (l & 15);
        int ch = (kk * 4 + (l >> 4)) ^ (R & 7);
        af[m] = *(const bf16x8*)(la + R * 64 + ch * 8);
      }
#pragma unroll
      for (int n = 0; n < FN; ++n) {
        int R = wc * WN + n * 16 + (l & 15);
        int ch = (kk * 4 + (l >> 4)) ^ (R & 7);
        bfr[n] = *(const bf16x8*)(lb + R * 64 + ch * 8);
      }
#pragma unroll
      for (int m = 0; m < FM; ++m)
#pragma unroll
        for (int n = 0; n < FN; ++n)
          acc[m][n] = __builtin_amdgcn_mfma_f32_16x16x32_bf16(af[m], bfr[n], acc[m][n], 0, 0, 0);
    }
  }
  const int rb  = m0 + wr * WM + ((l >> 4) * 4);
  const int cb0 = n0 + wc * WN + (l & 15);
#pragma unroll
  for (int m = 0; m < FM; ++m)
#pragma unroll
    for (int n = 0; n < FN; ++n) {
      int gcol = cb0 + n * 16;
#pragma unroll
      for (int j = 0; j < 4; ++j) {
        int grow = rb + m * 16 + j;
        float v = acc[m][n][j];
        if (MODE == 0) {
          float scv = (gcol < 512) ? qscale : 1.f;
          obf[(size_t)grow * N + gcol] = f2bf(v * scv);
        } else if (MODE == 1) {
          of[(size_t)grow * N + gcol] = v + cb[gcol] + add_[(size_t)grow * N + gcol];
        } else {
          float t = v + cb[gcol];
          float ge = 0.5f * t * (1.f + erff(t * 0.70710678118654752f));
          obf[(size_t)grow * N + gcol] = f2bf(ge);
        }
      }
    }
}

template<int MODE, int BM, int BN>
__global__ __launch_bounds__(256) void k_gemm(
    const u16* __restrict__ A, const u16* __restrict__ Bw,
    int M, int N, int K,
    u16* __restrict__ obf, float* __restrict__ of,
    const float* __restrict__ cb, const float* __restrict__ add_,
    float qscale) {
  gemm_body<MODE, BM, BN>(blockIdx.x, blockIdx.y, A, Bw, M, N, K, obf, of, cb, add_, qscale);
}

// ---------------- pair bias body: bias[b,h,i,j] = sum_c pair[b,i,j,c]*wp[h,c] ----------------
__device__ __forceinline__ void bias_body(int blk, const float* __restrict__ pair,
    const float* __restrict__ wp, u16* __restrict__ bias) {
  const int tid = threadIdx.x, l = tid & 63, w = tid >> 6;
  bf16x8 bfrag[2];
  {
    const float* wb = wp + (l & 15) * 64 + (l >> 4) * 8;
#pragma unroll
    for (int kk = 0; kk < 2; ++kk) {
      float4 w0 = *(const float4*)(wb + kk * 32);
      float4 w1 = *(const float4*)(wb + kk * 32 + 4);
      bf16x8 bb;
      bb[0] = (short)f2bf(w0.x); bb[1] = (short)f2bf(w0.y);
      bb[2] = (short)f2bf(w0.z); bb[3] = (short)f2bf(w0.w);
      bb[4] = (short)f2bf(w1.x); bb[5] = (short)f2bf(w1.y);
      bb[6] = (short)f2bf(w1.z); bb[7] = (short)f2bf(w1.w);
      bfrag[kk] = bb;
    }
  }
  const size_t m_base = (size_t)blk * 1024 + w * 256;   // 1024 positions per block
  const f32x4 fz = {0.f, 0.f, 0.f, 0.f};
#pragma unroll 4
  for (int f = 0; f < 16; ++f) {
    size_t row = m_base + f * 16 + (l & 15);
    const float* pr = pair + row * 64 + (l >> 4) * 8;
    float4 p0 = *(const float4*)(pr);
    float4 p1 = *(const float4*)(pr + 4);
    float4 p2 = *(const float4*)(pr + 32);
    float4 p3 = *(const float4*)(pr + 36);
    bf16x8 a0, a1;
    a0[0] = (short)f2bf(p0.x); a0[1] = (short)f2bf(p0.y);
    a0[2] = (short)f2bf(p0.z); a0[3] = (short)f2bf(p0.w);
    a0[4] = (short)f2bf(p1.x); a0[5] = (short)f2bf(p1.y);
    a0[6] = (short)f2bf(p1.z); a0[7] = (short)f2bf(p1.w);
    a1[0] = (short)f2bf(p2.x); a1[1] = (short)f2bf(p2.y);
    a1[2] = (short)f2bf(p2.z); a1[3] = (short)f2bf(p2.w);
    a1[4] = (short)f2bf(p3.x); a1[5] = (short)f2bf(p3.y);
    a1[6] = (short)f2bf(p3.z); a1[7] = (short)f2bf(p3.w);
    f32x4 acc = __builtin_amdgcn_mfma_f32_16x16x32_bf16(a0, bfrag[0], fz, 0, 0, 0);
    acc = __builtin_amdgcn_mfma_f32_16x16x32_bf16(a1, bfrag[1], acc, 0, 0, 0);
    size_t m0c = m_base + f * 16 + (l >> 4) * 4;
    size_t b = m0c >> 20;
    size_t ij = m0c & 1048575;
    u16* dst = bias + (((b << 4) + (l & 15)) << 20) + ij;
    s16x4 ov;
    ov[0] = (short)f2bf(acc[0]); ov[1] = (short)f2bf(acc[1]);
    ov[2] = (short)f2bf(acc[2]); ov[3] = (short)f2bf(acc[3]);
    *(s16x4*)dst = ov;
  }
}

// ---------------- mega: QKV GEMM (blocks 0..191, 128x128) ∥ pair bias (192..2239) ----------------
__global__ __launch_bounds__(256) void k_mega(
    const u16* __restrict__ h_bf, const u16* __restrict__ qkvw,
    u16* __restrict__ qkv_bf, float qscale,
    const float* __restrict__ pair, const float* __restrict__ wp,
    u16* __restrict__ bias) {
  if (blockIdx.x < 192) {
    gemm_body<0, 128, 128>(blockIdx.x % 12, blockIdx.x / 12,
        h_bf, qkvw, 2048, 1536, 512, qkv_bf, nullptr, nullptr, nullptr, qscale);
  } else {
    bias_body(blockIdx.x - 192, pair, wp, bias);
  }
}

// ---------------- flash attention, swapped QK^T (S^T = mfma(K,Q)) ----------------
// Each lane owns ONE i-row (i = w*16 + (l&15)); row softmax is in-register + 2 shuffles.
// kl padded [64][40] (2-way banks); vt/bl/pl XOR-swizzled (col ^ ((row&7)<<3)).
__global__ __launch_bounds__(256) void k_attn(const u16* __restrict__ qkv,
    const u16* __restrict__ bias, u16* __restrict__ ob) {
  __shared__ u16 kl[64 * 40];      // K tile [j][d], d padded 32->40
  __shared__ u16 vt[32 * 64];      // V^T [d][j], swizzled
  __shared__ u16 bl[64 * 64];      // bias tile [i][j], swizzled
  __shared__ u16 pl[4][16 * 64];   // per-wave P [i][j], swizzled
  __shared__ float cw[4][16];      // per-wave corr broadcast
  __shared__ float lw[4][16];      // per-wave lsum broadcast
  const int tid = threadIdx.x, l = tid & 63, w = tid >> 6;
  const int g = l >> 4;            // 16-lane group 0..3
  const int i0 = blockIdx.x * 64;
  const int h  = blockIdx.y;
  const int b  = blockIdx.z;
  const u16* base = qkv + (size_t)b * 1024 * 1536 + h * 32;
  // Q B-frag in registers: n=i=l&15 (wave strip), k=d=g*8..+7
  const int ib = w * 16 + (l & 15);       // block-local i row this lane owns
  const bf16x8 qb = *(const bf16x8*)(base + (size_t)(i0 + ib) * 1536 + g * 8);
  float mr = -1e30f, lr = 0.f;
  f32x4 oa[2];
  const f32x4 fz = {0.f, 0.f, 0.f, 0.f};
  oa[0] = fz; oa[1] = fz;
  const size_t bbase = ((size_t)(b * 16 + h) * 1024 + (size_t)i0) * 1024;
  u16* plw = &pl[w][0];
  for (int jt = 0; jt < 16; ++jt) {
    const int j0 = jt * 64;
    __syncthreads();    // prev iter's reads of kl/vt/bl complete
    {
      int row = tid >> 2, d8 = (tid & 3) * 8;
      *(bf16x8*)(kl + row * 40 + d8) = *(const bf16x8*)(base + 512 + (size_t)(j0 + row) * 1536 + d8);
      bf16x8 vv = *(const bf16x8*)(base + 1024 + (size_t)(j0 + row) * 1536 + d8);
#pragma unroll
      for (int e = 0; e < 8; ++e)
        vt[(d8 + e) * 64 + (row ^ (e << 3))] = (u16)vv[e];
      int il = tid >> 2, jl = (tid & 3) * 16;
      int v_ = (il & 7) << 3;
      const u16* bs = bias + bbase + (size_t)il * 1024 + j0 + jl;
      *(bf16x8*)(bl + il * 64 + (jl ^ v_))       = *(const bf16x8*)bs;
      *(bf16x8*)(bl + il * 64 + ((jl + 8) ^ v_)) = *(const bf16x8*)(bs + 8);
    }
    __syncthreads();
    // S^T[j, i] = K[j,:]·Q[i,:]: 4 MFMAs, lane holds j = jf*16 + g*4 + r for its i=ib
    f32x4 s[4];
#pragma unroll
    for (int jf = 0; jf < 4; ++jf) {
      int R = jf * 16 + (l & 15);
      bf16x8 ak = *(const bf16x8*)(kl + R * 40 + g * 8);
      s[jf] = __builtin_amdgcn_mfma_f32_16x16x32_bf16(ak, qb, fz, 0, 0, 0);
    }
    // add bias: 4x ds_read_b64
#pragma unroll
    for (int jf = 0; jf < 4; ++jf) {
      int c = jf * 16 + g * 4;
      s16x4 bv = *(const s16x4*)(bl + ib * 64 + (c ^ ((ib & 7) << 3)));
#pragma unroll
      for (int r = 0; r < 4; ++r) s[jf][r] += bf2f((u16)bv[r]);
    }
    // in-register row softmax (row i=ib, 16 of 64 j's per lane; groups hold the rest)
    float rm = s[0][0];
#pragma unroll
    for (int jf = 0; jf < 4; ++jf)
#pragma unroll
      for (int r = 0; r < 4; ++r) rm = fmaxf(rm, s[jf][r]);
    rm = fmaxf(rm, __shfl_xor(rm, 16));
    rm = fmaxf(rm, __shfl_xor(rm, 32));
    float mn = fmaxf(mr, rm);
    float corr = __expf(mr - mn);
    float p[4][4];
    float rs = 0.f;
#pragma unroll
    for (int jf = 0; jf < 4; ++jf)
#pragma unroll
      for (int r = 0; r < 4; ++r) { p[jf][r] = __expf(s[jf][r] - mn); rs += p[jf][r]; }
    rs += __shfl_xor(rs, 16);
    rs += __shfl_xor(rs, 32);
    lr = lr * corr + rs;
    mr = mn;
    if (l < 16) cw[w][l] = corr;   // group-0 copy (all copies identical)
    // pack P -> pl (4x ds_write_b64), layout [i][j] matches PV A-frag reads
#pragma unroll
    for (int jf = 0; jf < 4; ++jf) {
      s16x4 pv;
#pragma unroll
      for (int r = 0; r < 4; ++r) pv[r] = (short)f2bf(p[jf][r]);
      int c = jf * 16 + g * 4;
      *(s16x4*)(plw + (l & 15) * 64 + (c ^ (((l & 15) & 7) << 3))) = pv;
    }
    // rescale O by corr of the O-fragment's rows (i = g*4 + r)
    float cr0 = cw[w][g * 4 + 0], cr1 = cw[w][g * 4 + 1];
    float cr2 = cw[w][g * 4 + 2], cr3 = cw[w][g * 4 + 3];
#pragma unroll
    for (int n = 0; n < 2; ++n) {
      oa[n][0] *= cr0; oa[n][1] *= cr1; oa[n][2] *= cr2; oa[n][3] *= cr3;
    }
    // PV: O[i,d] += P[i,:] V[:,d]
#pragma unroll
    for (int kk = 0; kk < 2; ++kk) {
      int ip = l & 15;
      bf16x8 pa = *(const bf16x8*)(plw + ip * 64 + ((kk * 32 + g * 8) ^ ((ip & 7) << 3)));
#pragma unroll
      for (int n = 0; n < 2; ++n) {
        int dp = n * 16 + (l & 15);
        bf16x8 vb = *(const bf16x8*)(vt + dp * 64 + ((kk * 32 + g * 8) ^ ((dp & 7) << 3)));
        oa[n] = __builtin_amdgcn_mfma_f32_16x16x32_bf16(pa, vb, oa[n], 0, 0, 0);
      }
    }
  }
  if (l < 16) lw[w][l] = lr;
  float lv0 = lw[w][g * 4 + 0], lv1 = lw[w][g * 4 + 1];
  float lv2 = lw[w][g * 4 + 2], lv3 = lw[w][g * 4 + 3];
#pragma unroll
  for (int n = 0; n < 2; ++n) {
    float lvr[4] = {lv0, lv1, lv2, lv3};
#pragma unroll
    for (int r = 0; r < 4; ++r) {
      float v = oa[n][r] / lvr[r];
      ob[(size_t)(b * 1024 + i0 + w * 16 + g * 4 + r) * 512 + h * 32 + n * 16 + (l & 15)] = f2bf(v);
    }
  }
}

extern "C" void kernel_launch(void* const* d_in, const int* in_sizes, int n_in,
                              void* d_out, int out_size, void* d_ws, size_t ws_size,
                              hipStream_t stream) {
  const float* x    = (const float*)d_in[0];
  const float* pair = (const float*)d_in[1];
  const float* tc   = (const float*)d_in[2];
  const float* ln1g = (const float*)d_in[3];
  const float* ln1b = (const float*)d_in[4];
  const float* a1w  = (const float*)d_in[5];
  const float* a1b  = (const float*)d_in[6];
  const float* wq   = (const float*)d_in[7];
  const float* wk   = (const float*)d_in[8];
  const float* wv   = (const float*)d_in[9];
  const float* wp   = (const float*)d_in[10];
  const float* wo   = (const float*)d_in[11];
  const float* bo   = (const float*)d_in[12];
  const float* ln2g = (const float*)d_in[13];
  const float* ln2b = (const float*)d_in[14];
  const float* a2w  = (const float*)d_in[15];
  const float* a2b  = (const float*)d_in[16];
  const float* w1   = (const float*)d_in[17];
  const float* b1   = (const float*)d_in[18];
  const float* w2   = (const float*)d_in[19];
  const float* b2   = (const float*)d_in[20];
  float* out = (float*)d_out;

  char* ws = (char*)d_ws;
  size_t off = 0;
  auto alloc = [&](size_t bytes) {
    size_t cur = off;
    off += (bytes + 255) & ~(size_t)255;
    return (void*)(ws + cur);
  };
  float* ss1    = (float*)alloc(2 * 1024 * 4);
  float* ss2    = (float*)alloc(2 * 1024 * 4);
  u16*   qkvw   = (u16*)alloc((size_t)1536 * 512 * 2);
  u16*   wo_bf  = (u16*)alloc((size_t)512 * 512 * 2);
  u16*   w1_bf  = (u16*)alloc((size_t)2048 * 512 * 2);
  u16*   w2_bf  = (u16*)alloc((size_t)512 * 2048 * 2);
  u16*   h_bf   = (u16*)alloc((size_t)2048 * 512 * 2);
  u16*   qkv_bf = (u16*)alloc((size_t)2048 * 1536 * 2);
  u16*   o_bf   = (u16*)alloc((size_t)2048 * 512 * 2);
  u16*   h2_bf  = (u16*)alloc((size_t)2048 * 512 * 2);
  float* xmid   = (float*)alloc((size_t)2048 * 512 * 4);
  u16*   mid_bf = (u16*)alloc((size_t)2048 * 2048 * 2);
  u16*   bias_bf= (u16*)alloc((size_t)2 * 16 * 1024 * 1024 * 2);
  (void)ws_size; (void)in_sizes; (void)n_in; (void)out_size;

  // weights -> bf16 + adaLN scale/shift, one launch
  k_pre<<<4096, 256, 0, stream>>>(wq, wk, wv, wo, w1, w2,
                                  qkvw, wo_bf, w1_bf, w2_bf,
                                  tc, a1w, a1b, a2w, a2b, ss1, ss2);

  // adaLN1 -> h (bf16)
  k_adaln<<<512, 256, 0, stream>>>(x, ln1g, ln1b, ss1, h_bf);

  // QKV GEMM (192 blocks, 128x128) ∥ pair bias (2048 blocks) in one dispatch
  k_mega<<<2240, 256, 0, stream>>>(h_bf, qkvw, qkv_bf, 0.17677669529663687f,
                                   pair, wp, bias_bf);

  // flash attention
  k_attn<<<dim3(16, 16, 2), 256, 0, stream>>>(qkv_bf, bias_bf, o_bf);

  // out proj + residual: xmid = x + O@wo^T + bo (f32); 64x64 tiles
  k_gemm<1, 64, 64><<<dim3(8, 32), 256, 0, stream>>>(o_bf, wo_bf, 2048, 512, 512,
      nullptr, xmid, bo, x, 1.f);

  // adaLN2 -> h2 (bf16)
  k_adaln<<<512, 256, 0, stream>>>(xmid, ln2g, ln2b, ss2, h2_bf);

  // FFN1 + exact GELU -> mid (bf16); 64x128 tiles, 512 blocks
  k_gemm<2, 64, 128><<<dim3(16, 32), 256, 0, stream>>>(h2_bf, w1_bf, 2048, 2048, 512,
      mid_bf, nullptr, b1, nullptr, 1.f);

  // FFN2 + residual -> out (f32); 64x64 tiles
  k_gemm<1, 64, 64><<<dim3(8, 32), 256, 0, stream>>>(mid_bf, w2_bf, 2048, 512, 2048,
      nullptr, out, b2, xmid, 1.f);
}